// Round 2
// baseline (742.639 us; speedup 1.0000x reference)
//
#include <hip/hip_runtime.h>

// SSIM loss, fused: (32,3,512,512) fp32, 11x11 avg pools, out = 1 - mean(ssim_map).
//
// R5 = R3 geometry (proven fastest) + targeted fixes:
//  - 64x32 output tile, NROWS=42 halo rows, LDS row stride 65 float4.
//  - Stage B: branch-free loads (clamped addr + mask-mul, all 16 float4 loads
//    issue under one vmcnt wait; R3's per-iteration if-guards could serialize
//    into 8 branch blocks).
//  - Stage B writes: XOR swizzle col' = xr*16 + (k ^ 2*xr). R3's layout had
//    bank-group = (j+k)&7, xr-independent -> 4-way write conflicts (1.24e7
//    conflict cycles = 11% of kernel). New: within any aligned 8-lane phase
//    (2 j x 4 xr) groups (j + (k^2xr))&7 cover all 8 -> conflict-free.
//    Stage C reads at cx = (x&48)|((x&15)^(2*(x>>4))): off^m bijective within
//    each phase -> still conflict-free.
//  - Finalize fused into last block (atomic counter + threadfence); removes
//    the <<<1,1>>> finalize dispatch. Workspace: {double accum; uint counter}.

#define IMGW 512
#define IMGPIX (IMGW * IMGW)
#define TW 64
#define TH 32
#define NROWS 42          // TH + 10 halo
#define SH 65             // LDS row stride in float4
#define NIMG 96
#define NBLOCKS (8 * 16 * 96)

__global__ __launch_bounds__(256, 3)
void ssim_partial(const float* __restrict__ pred,
                  const float* __restrict__ target,
                  double* __restrict__ accum,
                  float* __restrict__ out)
{
    __shared__ float4 sH[NROWS * SH];   // 43680 B
    __shared__ float  wpart[4];

    const int tid = threadIdx.x;
    const int bx = blockIdx.x, by = blockIdx.y, img = blockIdx.z;
    const float* __restrict__ p = pred   + (size_t)img * IMGPIX;
    const float* __restrict__ t = target + (size_t)img * IMGPIX;
    const int gy0 = by * TH;

    // ---- Stage B: horizontal 11-sums of 4 planes, sliding in registers ----
    if (tid < NROWS * 4) {
        const int j  = tid >> 2;          // halo row 0..41
        const int xr = tid & 3;           // 16-col run
        const int rv = gy0 - 5 + j;       // image row (may be OOB)
        const bool rowok = (unsigned)rv < (unsigned)IMGW;
        const int rvc = rv < 0 ? 0 : (rv > IMGW - 1 ? IMGW - 1 : rv);
        const int xbase = bx * TW + xr * 16;

        float fp[32], ft[32];
#pragma unroll
        for (int c = 0; c < 8; ++c) {
            const int gx = xbase - 8 + 4 * c;     // multiple of 4 -> aligned float4
            const bool ok = rowok && ((unsigned)gx < (unsigned)IMGW);
            const int gxc = gx < 0 ? 0 : (gx > IMGW - 4 ? IMGW - 4 : gx);
            const size_t off = (size_t)rvc * IMGW + gxc;
            const float4 pv = *(const float4*)(p + off);
            const float4 tv = *(const float4*)(t + off);
            const float m = ok ? 1.f : 0.f;
            fp[4*c+0] = pv.x * m; fp[4*c+1] = pv.y * m;
            fp[4*c+2] = pv.z * m; fp[4*c+3] = pv.w * m;
            ft[4*c+0] = tv.x * m; ft[4*c+1] = tv.y * m;
            ft[4*c+2] = tv.z * m; ft[4*c+3] = tv.w * m;
        }
        // output x = xbase+k has window indices i = k+3 .. k+13 (i: x = xbase-8+i)
        float s1 = 0.f, s2 = 0.f, s3 = 0.f, s4 = 0.f;
#pragma unroll
        for (int i = 3; i <= 13; ++i) {
            s1 += fp[i];
            s2 += ft[i];
            s3 += fp[i] * fp[i] + ft[i] * ft[i];
            s4 += fp[i] * ft[i];
        }
        const int wbase = j * SH + xr * 16;
        const int msw = xr << 1;          // swizzle key: 0,2,4,6
#pragma unroll
        for (int k = 0; k < 16; ++k) {
            if (k > 0) {
                const int a = k + 13, b = k + 2;
                s1 += fp[a] - fp[b];
                s2 += ft[a] - ft[b];
                s3 += (fp[a] * fp[a] + ft[a] * ft[a])
                    - (fp[b] * fp[b] + ft[b] * ft[b]);
                s4 += fp[a] * ft[a] - fp[b] * ft[b];
            }
            sH[wbase + (k ^ msw)] = make_float4(s1, s2, s3, s4);
        }
    }
    __syncthreads();

    // ---- Stage C: vertical 11-sums (lane = x), SSIM formula ----
    const float inv = 1.0f / 121.0f;
    const float C1 = 1e-4f, C2 = 9e-4f;
    const int lane = tid & 63;
    const int w    = tid >> 6;
    const int ry0  = w * 8;               // 8 output rows per wave
    // un-swizzled read column for x = lane (same for every row)
    const int cx = (lane & 48) | ((lane & 15) ^ ((lane >> 3) & 6));

    float4 r[8];
    float4 S = {0.f, 0.f, 0.f, 0.f};
#pragma unroll
    for (int i = 0; i < 8; ++i) {
        r[i] = sH[(ry0 + i) * SH + cx];
        S.x += r[i].x; S.y += r[i].y; S.z += r[i].z; S.w += r[i].w;
    }
    {
        const float4 a8 = sH[(ry0 + 8) * SH + cx];
        const float4 a9 = sH[(ry0 + 9) * SH + cx];
        S.x += a8.x + a9.x; S.y += a8.y + a9.y;
        S.z += a8.z + a9.z; S.w += a8.w + a9.w;
    }
    float local = 0.f;
#pragma unroll
    for (int k = 0; k < 8; ++k) {
        const float4 nw = sH[(ry0 + 10 + k) * SH + cx];
        const float W1 = S.x + nw.x;      // 11-row window sums
        const float W2 = S.y + nw.y;
        const float W3 = S.z + nw.z;
        const float W4 = S.w + nw.w;
        // advance running 10-row sum
        S.x = W1 - r[k].x; S.y = W2 - r[k].y;
        S.z = W3 - r[k].z; S.w = W4 - r[k].w;

        const float mu1 = W1 * inv, mu2 = W2 * inv;
        const float E3  = W3 * inv, E12 = W4 * inv;
        const float mu11 = mu1 * mu1, mu22 = mu2 * mu2, mu12 = mu1 * mu2;
        const float num = (2.f * mu12 + C1) * (2.f * (E12 - mu12) + C2);
        const float den = (mu11 + mu22 + C1) * ((E3 - mu11 - mu22) + C2);
        local += num / den;
    }

    // ---- block reduce -> one double atomic; last block finalizes ----
#pragma unroll
    for (int off = 32; off > 0; off >>= 1)
        local += __shfl_down(local, off, 64);
    if ((tid & 63) == 0) wpart[tid >> 6] = local;
    __syncthreads();
    if (tid == 0) {
        const double part = (double)(wpart[0] + wpart[1] + wpart[2] + wpart[3]);
        atomicAdd(accum, part);
        __threadfence();
        unsigned* cnt = (unsigned*)(accum + 1);
        if (atomicAdd(cnt, 1u) == (unsigned)(NBLOCKS - 1)) {
            const double total = atomicAdd(accum, 0.0);   // coherent read
            out[0] = (float)(1.0 - total / 25165824.0);   // 32*3*512*512
        }
    }
}

extern "C" void kernel_launch(void* const* d_in, const int* in_sizes, int n_in,
                              void* d_out, int out_size, void* d_ws, size_t ws_size,
                              hipStream_t stream) {
    const float* pred   = (const float*)d_in[0];
    const float* target = (const float*)d_in[1];
    float* out = (float*)d_out;
    double* accum = (double*)d_ws;

    hipMemsetAsync(d_ws, 0, 16, stream);   // {accum, counter}

    dim3 grid(IMGW / TW, IMGW / TH, NIMG);  // 8 x 16 x 96
    dim3 block(256);
    ssim_partial<<<grid, block, 0, stream>>>(pred, target, accum, out);
}

// Round 3
// 266.888 us; speedup vs baseline: 2.7826x; 2.7826x over previous
//
#include <hip/hip_runtime.h>

// SSIM loss, fused: (32,3,512,512) fp32, 11x11 avg pools, out = 1 - mean(ssim_map).
//
// R6 = persistent pipelined blocks + verified R5 swizzle + R3 guarded loads.
//  - 768 blocks (3/CU), each processes 16 tiles (stride 768). Per tile:
//      StageB(regs->LDS) | barrier | issue loads(tile+768) | StageC | barrier
//    Next tile's 32 float4 loads overlap StageC compute; the barrier's vmcnt
//    drain lands after ~200 wave-inst of cover. Removes per-block launch/fill
//    cost (was: 12288 one-shot blocks, each eating full HBM latency serially).
//  - LDS writes: XOR swizzle col' = xr*16 + (k ^ 2*xr)  [verified R5:
//    SQ_LDS_BANK_CONFLICT 1.24e7 -> 2.2e6]. Reads at
//    cx = (x&48)|((x&15)^(2*(x>>4))), conflict-free.
//  - Finalize back to separate <<<1,1>>> kernel. R5's fused finalize
//    (__threadfence per block = device-scope L2 writeback x 12288) caused the
//    3.5x regression: dur 612us, VALUBusy 7.8, WRITE_SIZE 2x. Never again.
//  - Per-tile float partial -> double accumulator per thread; one double
//    atomicAdd per block (768 total).

#define IMGW 512
#define IMGPIX (IMGW * IMGW)
#define TW 64
#define TH 32
#define NROWS 42          // TH + 10 halo
#define SH 65             // LDS row stride in float4
#define NIMG 96
#define NTILES (8 * 16 * NIMG)     // 12288
#define PBLOCKS 768                // 3 per CU
#define TPB (NTILES / PBLOCKS)     // 16 tiles per block

__global__ __launch_bounds__(256, 3)
void ssim_partial(const float* __restrict__ pred,
                  const float* __restrict__ target,
                  double* __restrict__ accum)
{
    __shared__ float4 sH[NROWS * SH];   // 43680 B
    __shared__ double wpart[4];

    const int tid   = threadIdx.x;
    const bool loader = tid < NROWS * 4;      // 168 loader threads
    const int j     = tid >> 2;               // halo row 0..41
    const int xr    = tid & 3;                // 16-col run
    const int msw   = xr << 1;                // write-swizzle key 0,2,4,6
    const int lane  = tid & 63;
    const int w     = tid >> 6;
    const int ry0   = w * 8;                  // 8 output rows per wave
    const int cx    = (lane & 48) | ((lane & 15) ^ ((lane >> 3) & 6));
    const float inv = 1.0f / 121.0f;
    const float C1 = 1e-4f, C2 = 9e-4f;

    float fp[32], ft[32];

    auto prefetch = [&](int tau) {
        const int bx  = tau & 7;
        const int by  = (tau >> 3) & 15;
        const int img = tau >> 7;
        const float* __restrict__ p = pred   + (size_t)img * IMGPIX;
        const float* __restrict__ t = target + (size_t)img * IMGPIX;
        const int rv = by * TH - 5 + j;       // image row (may be OOB -> zeros)
        const bool rowok = (unsigned)rv < (unsigned)IMGW;
        const int xbase = bx * TW + xr * 16;
#pragma unroll
        for (int c = 0; c < 8; ++c) {
            const int gx = xbase - 8 + 4 * c; // multiple of 4 -> aligned float4
            float4 pv = {0.f, 0.f, 0.f, 0.f};
            float4 tv = {0.f, 0.f, 0.f, 0.f};
            if (rowok && (unsigned)gx < (unsigned)IMGW) {
                const size_t off = (size_t)rv * IMGW + gx;
                pv = *(const float4*)(p + off);
                tv = *(const float4*)(t + off);
            }
            fp[4*c+0] = pv.x; fp[4*c+1] = pv.y; fp[4*c+2] = pv.z; fp[4*c+3] = pv.w;
            ft[4*c+0] = tv.x; ft[4*c+1] = tv.y; ft[4*c+2] = tv.z; ft[4*c+3] = tv.w;
        }
    };

    if (loader) prefetch(blockIdx.x);

    double locald = 0.0;
    int tau = blockIdx.x;
    for (int it = 0; it < TPB; ++it, tau += PBLOCKS) {
        // ---- Stage B: horizontal 11-sums of 4 planes from regs, sliding ----
        if (loader) {
            float s1 = 0.f, s2 = 0.f, s3 = 0.f, s4 = 0.f;
#pragma unroll
            for (int i = 3; i <= 13; ++i) {
                s1 += fp[i];
                s2 += ft[i];
                s3 += fp[i] * fp[i] + ft[i] * ft[i];
                s4 += fp[i] * ft[i];
            }
            const int wbase = j * SH + xr * 16;
#pragma unroll
            for (int k = 0; k < 16; ++k) {
                if (k > 0) {
                    const int a = k + 13, b2 = k + 2;
                    s1 += fp[a] - fp[b2];
                    s2 += ft[a] - ft[b2];
                    s3 += (fp[a] * fp[a] + ft[a] * ft[a])
                        - (fp[b2] * fp[b2] + ft[b2] * ft[b2]);
                    s4 += fp[a] * ft[a] - fp[b2] * ft[b2];
                }
                sH[wbase + (k ^ msw)] = make_float4(s1, s2, s3, s4);
            }
        }
        __syncthreads();

        // issue next tile's loads; they complete under Stage C
        if (loader && it + 1 < TPB) prefetch(tau + PBLOCKS);

        // ---- Stage C: vertical 11-sums (lane = x), SSIM formula ----
        float4 r[8];
        float4 S = {0.f, 0.f, 0.f, 0.f};
#pragma unroll
        for (int i = 0; i < 8; ++i) {
            r[i] = sH[(ry0 + i) * SH + cx];
            S.x += r[i].x; S.y += r[i].y; S.z += r[i].z; S.w += r[i].w;
        }
        {
            const float4 a8 = sH[(ry0 + 8) * SH + cx];
            const float4 a9 = sH[(ry0 + 9) * SH + cx];
            S.x += a8.x + a9.x; S.y += a8.y + a9.y;
            S.z += a8.z + a9.z; S.w += a8.w + a9.w;
        }
        float tl = 0.f;
#pragma unroll
        for (int k = 0; k < 8; ++k) {
            const float4 nw = sH[(ry0 + 10 + k) * SH + cx];
            const float W1 = S.x + nw.x;      // 11-row window sums
            const float W2 = S.y + nw.y;
            const float W3 = S.z + nw.z;
            const float W4 = S.w + nw.w;
            S.x = W1 - r[k].x; S.y = W2 - r[k].y;
            S.z = W3 - r[k].z; S.w = W4 - r[k].w;

            const float mu1 = W1 * inv, mu2 = W2 * inv;
            const float E3  = W3 * inv, E12 = W4 * inv;
            const float mu11 = mu1 * mu1, mu22 = mu2 * mu2, mu12 = mu1 * mu2;
            const float num = (2.f * mu12 + C1) * (2.f * (E12 - mu12) + C2);
            const float den = (mu11 + mu22 + C1) * ((E3 - mu11 - mu22) + C2);
            tl += num / den;
        }
        locald += (double)tl;
        __syncthreads();                      // LDS safe to overwrite next iter
    }

    // ---- block reduce -> one double atomic per block ----
#pragma unroll
    for (int off = 32; off > 0; off >>= 1)
        locald += __shfl_down(locald, off, 64);
    if (lane == 0) wpart[w] = locald;
    __syncthreads();
    if (tid == 0)
        atomicAdd(accum, wpart[0] + wpart[1] + wpart[2] + wpart[3]);
}

__global__ void ssim_finalize(const double* __restrict__ accum,
                              float* __restrict__ out) {
    const double n = 25165824.0;  // 32*3*512*512
    out[0] = (float)(1.0 - accum[0] / n);
}

extern "C" void kernel_launch(void* const* d_in, const int* in_sizes, int n_in,
                              void* d_out, int out_size, void* d_ws, size_t ws_size,
                              hipStream_t stream) {
    const float* pred   = (const float*)d_in[0];
    const float* target = (const float*)d_in[1];
    float* out = (float*)d_out;
    double* accum = (double*)d_ws;

    hipMemsetAsync(d_ws, 0, sizeof(double), stream);

    ssim_partial<<<dim3(PBLOCKS), dim3(256), 0, stream>>>(pred, target, accum);
    ssim_finalize<<<1, 1, 0, stream>>>(accum, out);
}

// Round 4
// 261.486 us; speedup vs baseline: 2.8401x; 1.0207x over previous
//
#include <hip/hip_runtime.h>

// SSIM loss, fused: (32,3,512,512) fp32, 11x11 avg pools, out = 1 - mean(ssim_map).
//
// R7 = persistent vertical-strip streaming + LDS-only barriers.
//  - 768 blocks (3/CU, LDS 49152 B), block = one 64-wide x 512-tall strip,
//    16 chunks of 32 output rows. 48-row circular LDS ring of H = (Sum p,
//    Sum t, Sum p^2+t^2, Sum p*t) float4 rows; only 32 NEW rows staged per
//    chunk (vs 42/tile in R6: -24% stage-B work + loads).
//  - Stage B balanced: 32 rows x 8 runs(8 cols) = all 256 threads (R6: 168).
//  - Row swizzle col' = col ^ (slot&7), NBUF=48 multiple of 8 -> consecutive
//    slots have distinct keys mod 8 even across the ring wrap. Stores: 8
//    lanes/bank-group uniform; reads: per-row bijection. (R5-verified family.)
//  - Barriers are LDS-only: s_waitcnt lgkmcnt(0) + raw s_barrier (m201
//    pattern). NO vmcnt drain -> next chunk's 12 float4 prefetch loads stay
//    in flight across both barriers, consumed at next stage B (full cover).
//    sched_barrier(0) pins prefetch issue ahead of stage C.
//  - Division via v_rcp_f32 + 1 Newton step (absmax ~1e-7, was bit-exact).
//  - Finalize = separate <<<1,1>>> kernel (R5's fused-threadfence disaster).

#define IMGW 512
#define IMGPIX (IMGW * IMGW)
#define TW 64
#define CH 32            // output rows per chunk
#define NCHUNK 16        // 512 / CH
#define NBUF 48          // LDS row ring; multiple of 8, >= 42 live rows
#define PBLOCKS 768      // 8 col-strips x 96 images, 3 per CU

__global__ __launch_bounds__(256, 3)
void ssim_strip(const float* __restrict__ pred,
                const float* __restrict__ target,
                double* __restrict__ accum)
{
    __shared__ float4 sH[NBUF * 64];     // 49152 B -> 3 blocks/CU
    __shared__ double wpart[4];

    const int tid   = threadIdx.x;
    const int strip = blockIdx.x;
    const int img = strip >> 3, bx = strip & 7;
    const float* __restrict__ p = pred   + (size_t)img * IMGPIX;
    const float* __restrict__ t = target + (size_t)img * IMGPIX;

    const int j     = tid >> 3;          // staging row 0..31
    const int xr    = tid & 7;           // 8-col run
    const int xbase = bx * TW + xr * 8;
    const int lane  = tid & 63;
    const int w     = tid >> 6;

    float fp[24], ft[24];

    // load one halo row's 24-col span [xbase-8, xbase+16) into regs (0 if OOB)
    auto load_rows = [&](int r) {
        const bool rowok = (unsigned)r < (unsigned)IMGW;
        const size_t ro = (size_t)(r & 511) * IMGW;   // masked loads ignore OOB ro
#pragma unroll
        for (int c = 0; c < 6; ++c) {
            const int gx = xbase - 8 + 4 * c;         // multiple of 4 -> aligned
            float4 pv = {0.f, 0.f, 0.f, 0.f};
            float4 tv = {0.f, 0.f, 0.f, 0.f};
            if (rowok && (unsigned)gx < (unsigned)IMGW) {
                pv = *(const float4*)(p + ro + gx);
                tv = *(const float4*)(t + ro + gx);
            }
            fp[4*c+0]=pv.x; fp[4*c+1]=pv.y; fp[4*c+2]=pv.z; fp[4*c+3]=pv.w;
            ft[4*c+0]=tv.x; ft[4*c+1]=tv.y; ft[4*c+2]=tv.z; ft[4*c+3]=tv.w;
        }
    };

    // horizontal 11-sums of 4 planes from regs -> LDS ring slot sl (swizzled)
    auto stage_rows = [&](int sl) {
        float s1=0.f, s2=0.f, s3=0.f, s4=0.f;
#pragma unroll
        for (int i = 3; i <= 13; ++i) {              // x = xbase+0 window
            s1 += fp[i]; s2 += ft[i];
            s3 += fp[i]*fp[i] + ft[i]*ft[i];
            s4 += fp[i]*ft[i];
        }
        const int rb  = sl << 6;
        const int key = sl & 7;
#pragma unroll
        for (int k = 0; k < 8; ++k) {
            if (k) {
                const int a = k + 13, b = k + 2;
                s1 += fp[a] - fp[b];
                s2 += ft[a] - ft[b];
                s3 += (fp[a]*fp[a] + ft[a]*ft[a]) - (fp[b]*fp[b] + ft[b]*ft[b]);
                s4 += fp[a]*ft[a] - fp[b]*ft[b];
            }
            sH[rb | ((xr*8 + k) ^ key)] = make_float4(s1, s2, s3, s4);
        }
    };

    // LDS-only barrier: do NOT drain vmcnt (prefetch loads stay in flight)
    auto barrier_lds = [&]() {
        asm volatile("s_waitcnt lgkmcnt(0)" ::: "memory");
        __builtin_amdgcn_s_barrier();
        asm volatile("" ::: "memory");
    };

    // ---- head: stage image rows -5..36 (slots (r+48)%48) ----
    load_rows(-5 + j);
    { int sl = j + 43; if (sl >= NBUF) sl -= NBUF; stage_rows(sl); }
    if (tid < 80) {                       // rows 27..36, j = 0..9
        load_rows(27 + j);
        stage_rows(27 + j);
    }
    barrier_lds();

    const float inv = 1.0f / 121.0f;
    const float C1 = 1e-4f, C2 = 9e-4f;

    int cs = 8*w + 43; if (cs >= NBUF) cs -= NBUF;   // slot(32c-5+8w), c=0
    int bs = 37;                                     // slot(32(c+1)+5), c=0
    double acc = 0.0;

    for (int c = 0; c < NCHUNK; ++c) {
        // prefetch next chunk's 32 new rows (r = 32(c+1)+5+j); in flight
        // through stage C + both barriers, consumed by next stage_rows.
        if (c + 1 < NCHUNK) load_rows(32*(c+1) + 5 + j);
        __builtin_amdgcn_sched_barrier(0);

        // ---- stage C: vertical 11-sums (lane = x), SSIM formula ----
        int sl = cs;
        float4 rr[8];
        float4 S = {0.f, 0.f, 0.f, 0.f};
#pragma unroll
        for (int i = 0; i < 10; ++i) {
            const float4 a = sH[(sl << 6) | (lane ^ (sl & 7))];
            if (i < 8) rr[i] = a;
            S.x += a.x; S.y += a.y; S.z += a.z; S.w += a.w;
            sl = (sl + 1 == NBUF) ? 0 : sl + 1;
        }
        float tl = 0.f;
#pragma unroll
        for (int k = 0; k < 8; ++k) {
            const float4 nw = sH[(sl << 6) | (lane ^ (sl & 7))];
            sl = (sl + 1 == NBUF) ? 0 : sl + 1;
            const float W1 = S.x + nw.x, W2 = S.y + nw.y;
            const float W3 = S.z + nw.z, W4 = S.w + nw.w;
            S.x = W1 - rr[k].x; S.y = W2 - rr[k].y;
            S.z = W3 - rr[k].z; S.w = W4 - rr[k].w;

            const float mu1 = W1*inv, mu2 = W2*inv;
            const float E3  = W3*inv, E12 = W4*inv;
            const float mu11 = mu1*mu1, mu22 = mu2*mu2, mu12 = mu1*mu2;
            const float num = (2.f*mu12 + C1) * (2.f*(E12 - mu12) + C2);
            const float den = (mu11 + mu22 + C1) * ((E3 - mu11 - mu22) + C2);
            float rdn = __builtin_amdgcn_rcpf(den);
            rdn = rdn * __builtin_fmaf(-den, rdn, 2.0f);   // 1 NR step
            tl += num * rdn;
        }
        acc += (double)tl;
        cs += CH; if (cs >= NBUF) cs -= NBUF;

        barrier_lds();                    // stage-C reads done -> ring writable

        if (c + 1 < NCHUNK) {
            int sl2 = bs + j; if (sl2 >= NBUF) sl2 -= NBUF;
            stage_rows(sl2);              // waits vmcnt on prefetch here
            bs += CH; if (bs >= NBUF) bs -= NBUF;
        }
        barrier_lds();                    // ring writes visible for next C
    }

    // ---- block reduce -> one double atomic per block ----
#pragma unroll
    for (int off = 32; off > 0; off >>= 1)
        acc += __shfl_down(acc, off, 64);
    if (lane == 0) wpart[w] = acc;
    __syncthreads();
    if (tid == 0)
        atomicAdd(accum, wpart[0] + wpart[1] + wpart[2] + wpart[3]);
}

__global__ void ssim_finalize(const double* __restrict__ accum,
                              float* __restrict__ out) {
    const double n = 25165824.0;  // 32*3*512*512
    out[0] = (float)(1.0 - accum[0] / n);
}

extern "C" void kernel_launch(void* const* d_in, const int* in_sizes, int n_in,
                              void* d_out, int out_size, void* d_ws, size_t ws_size,
                              hipStream_t stream) {
    const float* pred   = (const float*)d_in[0];
    const float* target = (const float*)d_in[1];
    float* out = (float*)d_out;
    double* accum = (double*)d_ws;

    hipMemsetAsync(d_ws, 0, sizeof(double), stream);

    ssim_strip<<<dim3(PBLOCKS), dim3(256), 0, stream>>>(pred, target, accum);
    ssim_finalize<<<1, 1, 0, stream>>>(accum, out);
}

// Round 5
// 250.974 us; speedup vs baseline: 2.9590x; 1.0419x over previous
//
#include <hip/hip_runtime.h>

// SSIM loss, fused: (32,3,512,512) fp32, 11x11 avg pools, out = 1 - mean(ssim_map).
//
// R8 = R7 with the store-phase bank conflict fixed (single change).
//  R7's swizzle col^(sl&7) was derived for R5's thread mapping (phase = 2j x
//  4xr). R7's mapping (j=tid>>3, xr=tid&7) makes a store phase = 1j x 8xr,
//  and col^(sl&7) has xr-independent low bits -> every stage-B b128 write was
//  ~8-way conflicted (SQ_LDS_BANK_CONFLICT 2.2e6 -> 2.245e7, ~36us of 122us).
//  Fix: phys = (xr*8+k) ^ (sl&7) ^ xr  (xr folded into low 3 bits).
//    store phase low3 = k^key^xr  -> all 8 bank-groups ✓
//    read (lane x):   phys low3 = (x&7)^(x>>3)^key; precompute
//    lx = lane ^ ((lane>>3)&7), read at (sl<<6)|(lx^(sl&7)); read phase
//    (fixed x>>3=g): m^g^key bijective ✓
//
//  Carried from R7 (all verified or neutral):
//  - 768 persistent blocks (3/CU), 64-wide x 512-tall strip, 16 chunks of 32
//    rows, 48-slot circular LDS ring, 32 new rows staged per chunk.
//  - Stage B: all 256 threads (32 rows x 8 col-runs).
//  - LDS-only barriers (lgkmcnt + raw s_barrier, no vmcnt drain); prefetch
//    issued before stage C, consumed by next stage B.
//  - rcp+NR division; separate <<<1,1>>> finalize (R5 threadfence lesson).

#define IMGW 512
#define IMGPIX (IMGW * IMGW)
#define TW 64
#define CH 32            // output rows per chunk
#define NCHUNK 16        // 512 / CH
#define NBUF 48          // LDS row ring; multiple of 8, >= 42 live rows
#define PBLOCKS 768      // 8 col-strips x 96 images, 3 per CU

__global__ __launch_bounds__(256, 3)
void ssim_strip(const float* __restrict__ pred,
                const float* __restrict__ target,
                double* __restrict__ accum)
{
    __shared__ float4 sH[NBUF * 64];     // 49152 B -> 3 blocks/CU
    __shared__ double wpart[4];

    const int tid   = threadIdx.x;
    const int strip = blockIdx.x;
    const int img = strip >> 3, bx = strip & 7;
    const float* __restrict__ p = pred   + (size_t)img * IMGPIX;
    const float* __restrict__ t = target + (size_t)img * IMGPIX;

    const int j     = tid >> 3;          // staging row 0..31
    const int xr    = tid & 7;           // 8-col run
    const int xbase = bx * TW + xr * 8;
    const int lane  = tid & 63;
    const int w     = tid >> 6;
    const int lx    = lane ^ ((lane >> 3) & 7);   // read-side swizzle base

    float fp[24], ft[24];

    // load one halo row's 24-col span [xbase-8, xbase+16) into regs (0 if OOB)
    auto load_rows = [&](int r) {
        const bool rowok = (unsigned)r < (unsigned)IMGW;
        const size_t ro = (size_t)(r & 511) * IMGW;   // masked loads ignore OOB ro
#pragma unroll
        for (int c = 0; c < 6; ++c) {
            const int gx = xbase - 8 + 4 * c;         // multiple of 4 -> aligned
            float4 pv = {0.f, 0.f, 0.f, 0.f};
            float4 tv = {0.f, 0.f, 0.f, 0.f};
            if (rowok && (unsigned)gx < (unsigned)IMGW) {
                pv = *(const float4*)(p + ro + gx);
                tv = *(const float4*)(t + ro + gx);
            }
            fp[4*c+0]=pv.x; fp[4*c+1]=pv.y; fp[4*c+2]=pv.z; fp[4*c+3]=pv.w;
            ft[4*c+0]=tv.x; ft[4*c+1]=tv.y; ft[4*c+2]=tv.z; ft[4*c+3]=tv.w;
        }
    };

    // horizontal 11-sums of 4 planes from regs -> LDS ring slot sl (swizzled)
    auto stage_rows = [&](int sl) {
        float s1=0.f, s2=0.f, s3=0.f, s4=0.f;
#pragma unroll
        for (int i = 3; i <= 13; ++i) {              // x = xbase+0 window
            s1 += fp[i]; s2 += ft[i];
            s3 += fp[i]*fp[i] + ft[i]*ft[i];
            s4 += fp[i]*ft[i];
        }
        const int rb  = sl << 6;
        const int key = (sl & 7) ^ xr;               // xr folded into low bits
#pragma unroll
        for (int k = 0; k < 8; ++k) {
            if (k) {
                const int a = k + 13, b = k + 2;
                s1 += fp[a] - fp[b];
                s2 += ft[a] - ft[b];
                s3 += (fp[a]*fp[a] + ft[a]*ft[a]) - (fp[b]*fp[b] + ft[b]*ft[b]);
                s4 += fp[a]*ft[a] - fp[b]*ft[b];
            }
            sH[rb | ((xr*8 + k) ^ key)] = make_float4(s1, s2, s3, s4);
        }
    };

    // LDS-only barrier: do NOT drain vmcnt (prefetch loads stay in flight)
    auto barrier_lds = [&]() {
        asm volatile("s_waitcnt lgkmcnt(0)" ::: "memory");
        __builtin_amdgcn_s_barrier();
        asm volatile("" ::: "memory");
    };

    // ---- head: stage image rows -5..36 (slots (r+48)%48) ----
    load_rows(-5 + j);
    { int sl = j + 43; if (sl >= NBUF) sl -= NBUF; stage_rows(sl); }
    if (tid < 80) {                       // rows 27..36, j = 0..9
        load_rows(27 + j);
        stage_rows(27 + j);
    }
    barrier_lds();

    const float inv = 1.0f / 121.0f;
    const float C1 = 1e-4f, C2 = 9e-4f;

    int cs = 8*w + 43; if (cs >= NBUF) cs -= NBUF;   // slot(32c-5+8w), c=0
    int bs = 37;                                     // slot(32(c+1)+5), c=0
    double acc = 0.0;

    for (int c = 0; c < NCHUNK; ++c) {
        // prefetch next chunk's 32 new rows (r = 32(c+1)+5+j); in flight
        // through stage C + both barriers, consumed by next stage_rows.
        if (c + 1 < NCHUNK) load_rows(32*(c+1) + 5 + j);
        __builtin_amdgcn_sched_barrier(0);

        // ---- stage C: vertical 11-sums (lane = x), SSIM formula ----
        int sl = cs;
        float4 rr[8];
        float4 S = {0.f, 0.f, 0.f, 0.f};
#pragma unroll
        for (int i = 0; i < 10; ++i) {
            const float4 a = sH[(sl << 6) | (lx ^ (sl & 7))];
            if (i < 8) rr[i] = a;
            S.x += a.x; S.y += a.y; S.z += a.z; S.w += a.w;
            sl = (sl + 1 == NBUF) ? 0 : sl + 1;
        }
        float tl = 0.f;
#pragma unroll
        for (int k = 0; k < 8; ++k) {
            const float4 nw = sH[(sl << 6) | (lx ^ (sl & 7))];
            sl = (sl + 1 == NBUF) ? 0 : sl + 1;
            const float W1 = S.x + nw.x, W2 = S.y + nw.y;
            const float W3 = S.z + nw.z, W4 = S.w + nw.w;
            S.x = W1 - rr[k].x; S.y = W2 - rr[k].y;
            S.z = W3 - rr[k].z; S.w = W4 - rr[k].w;

            const float mu1 = W1*inv, mu2 = W2*inv;
            const float E3  = W3*inv, E12 = W4*inv;
            const float mu11 = mu1*mu1, mu22 = mu2*mu2, mu12 = mu1*mu2;
            const float num = (2.f*mu12 + C1) * (2.f*(E12 - mu12) + C2);
            const float den = (mu11 + mu22 + C1) * ((E3 - mu11 - mu22) + C2);
            float rdn = __builtin_amdgcn_rcpf(den);
            rdn = rdn * __builtin_fmaf(-den, rdn, 2.0f);   // 1 NR step
            tl += num * rdn;
        }
        acc += (double)tl;
        cs += CH; if (cs >= NBUF) cs -= NBUF;

        barrier_lds();                    // stage-C reads done -> ring writable

        if (c + 1 < NCHUNK) {
            int sl2 = bs + j; if (sl2 >= NBUF) sl2 -= NBUF;
            stage_rows(sl2);              // waits vmcnt on prefetch here
            bs += CH; if (bs >= NBUF) bs -= NBUF;
        }
        barrier_lds();                    // ring writes visible for next C
    }

    // ---- block reduce -> one double atomic per block ----
#pragma unroll
    for (int off = 32; off > 0; off >>= 1)
        acc += __shfl_down(acc, off, 64);
    if (lane == 0) wpart[w] = acc;
    __syncthreads();
    if (tid == 0)
        atomicAdd(accum, wpart[0] + wpart[1] + wpart[2] + wpart[3]);
}

__global__ void ssim_finalize(const double* __restrict__ accum,
                              float* __restrict__ out) {
    const double n = 25165824.0;  // 32*3*512*512
    out[0] = (float)(1.0 - accum[0] / n);
}

extern "C" void kernel_launch(void* const* d_in, const int* in_sizes, int n_in,
                              void* d_out, int out_size, void* d_ws, size_t ws_size,
                              hipStream_t stream) {
    const float* pred   = (const float*)d_in[0];
    const float* target = (const float*)d_in[1];
    float* out = (float*)d_out;
    double* accum = (double*)d_ws;

    hipMemsetAsync(d_ws, 0, sizeof(double), stream);

    ssim_strip<<<dim3(PBLOCKS), dim3(256), 0, stream>>>(pred, target, accum);
    ssim_finalize<<<1, 1, 0, stream>>>(accum, out);
}